// Round 5
// baseline (619.092 us; speedup 1.0000x reference)
//
#include <hip/hip_runtime.h>
#include <hip/hip_cooperative_groups.h>
#include <cstddef>
#include <cstdint>

namespace cg = cooperative_groups;

// MinGRU: g/v/d = x@W{g,v,d}^T + b; xs = sigmoid(g)*tanh(v); a = 0.001+0.998*sigmoid(d)
// h_t = a_t*h_{t-1} + xs_t (causal scan over S). Output h [B,S,D] f32.
// B=4, S=4096, D=1024.
// R5: cvt + R3 GEMM + ONE cooperative scan kernel (xs/a live in registers across
// grid.sync phases; kills the 134 MB xs/a HBM round-trip). Fallback to R3's
// 3-pass scan if cooperative launch is unavailable.

typedef _Float16 f16;
typedef f16 f16x4 __attribute__((ext_vector_type(4)));
typedef f16 f16x8 __attribute__((ext_vector_type(8)));
typedef float f32x4 __attribute__((ext_vector_type(4)));

#define S_LEN 4096
#define D_DIM 1024
#define B_DIM 4
#define M_TOT (B_DIM * S_LEN)  // 16384
#define N_TOT (3 * D_DIM)      // 3072
#define K_TOT D_DIM            // 1024

#define CLEN 16
#define CPB (S_LEN / CLEN)   // 256 chunks per batch
#define NCHUNK (B_DIM * CPB) // 1024

// ---------------- merged f32 -> f16 convert: x then Wg|Wv|Wd ----------------
__device__ __forceinline__ void cvt8(const float* s, f16* d) {
  f32x4 a = *(const f32x4*)s;
  f32x4 b = *(const f32x4*)(s + 4);
  f16x8 o;
  o[0] = (f16)a[0]; o[1] = (f16)a[1]; o[2] = (f16)a[2]; o[3] = (f16)a[3];
  o[4] = (f16)b[0]; o[5] = (f16)b[1]; o[6] = (f16)b[2]; o[7] = (f16)b[3];
  *(f16x8*)d = o;
}

__global__ void cvt_all_kernel(const float* __restrict__ x, const float* __restrict__ w0,
                               const float* __restrict__ w1, const float* __restrict__ w2,
                               f16* __restrict__ Ah, f16* __restrict__ Bh) {
  int i = (blockIdx.x * 256 + threadIdx.x) * 8;
  if (i < M_TOT * K_TOT) {
    cvt8(x + i, Ah + i);
  } else {
    int w = i - M_TOT * K_TOT;
    int sel = w >> 20;
    int loc = w & 1048575;
    const float* s = (sel == 0) ? w0 : (sel == 1) ? w1 : w2;
    cvt8(s + loc, Bh + w);
  }
}

// ---------------- GEMM (R3-proven): C[M,N] = A[M,K] * Bt[N,K]^T ----------------
#define BM 128
#define BN 128
#define BK 32
#define CT_PITCH 136

__device__ __forceinline__ void gl_lds16(const void* g, void* l) {
  __builtin_amdgcn_global_load_lds((const __attribute__((address_space(1))) void*)g,
                                   (__attribute__((address_space(3))) void*)l, 16, 0, 0);
}

__global__ __launch_bounds__(256) void gemm_f16_kernel(const f16* __restrict__ A,
                                                       const f16* __restrict__ Bt,
                                                       f16* __restrict__ C) {
  __shared__ __attribute__((aligned(16))) char smem[BM * CT_PITCH * 2];
  f16* As = (f16*)smem;
  f16* Bs = As + 4096;
  const int tid = threadIdx.x;
  const int lane = tid & 63;
  const int wave = tid >> 6;
  const int m0 = blockIdx.y * BM;
  const int n0 = blockIdx.x * BN;

  const int srow = tid >> 2;
  const int scol = (tid & 3) * 8;
  const f16* aG0 = A + (size_t)(m0 + srow) * K_TOT + scol;
  const f16* aG1 = A + (size_t)(m0 + srow + 64) * K_TOT + scol;
  const f16* bG0 = Bt + (size_t)(n0 + srow) * K_TOT + scol;
  const f16* bG1 = Bt + (size_t)(n0 + srow + 64) * K_TOT + scol;
  f16* aL0 = As + tid * 8;
  f16* aL1 = As + 2048 + tid * 8;
  f16* bL0 = Bs + tid * 8;
  f16* bL1 = Bs + 2048 + tid * 8;

  const int wm = (wave >> 1) * 64;
  const int wn = (wave & 1) * 64;
  const int lm = lane & 15;
  const int kq = (lane >> 4) * 8;

  f32x4 acc[4][4] = {};

  for (int k0 = 0; k0 < K_TOT; k0 += BK) {
    gl_lds16(aG0 + k0, aL0);
    gl_lds16(aG1 + k0, aL1);
    gl_lds16(bG0 + k0, bL0);
    gl_lds16(bG1 + k0, bL1);
    __syncthreads();
    f16x8 af[4], bf[4];
#pragma unroll
    for (int i = 0; i < 4; ++i)
      af[i] = *(const f16x8*)&As[(wm + i * 16 + lm) * BK + kq];
#pragma unroll
    for (int j = 0; j < 4; ++j)
      bf[j] = *(const f16x8*)&Bs[(wn + j * 16 + lm) * BK + kq];
#pragma unroll
    for (int i = 0; i < 4; ++i)
#pragma unroll
      for (int j = 0; j < 4; ++j)
        acc[i][j] = __builtin_amdgcn_mfma_f32_16x16x32_f16(af[i], bf[j], acc[i][j], 0, 0, 0);
    __syncthreads();
  }

  f16* Ct = (f16*)smem;
  const int r0 = wm + (lane >> 4) * 4;
  const int c0 = wn + (lane & 15);
#pragma unroll
  for (int i = 0; i < 4; ++i)
#pragma unroll
    for (int j = 0; j < 4; ++j)
#pragma unroll
      for (int r = 0; r < 4; ++r)
        Ct[(r0 + i * 16 + r) * CT_PITCH + c0 + j * 16] = (f16)acc[i][j][r];
  __syncthreads();
#pragma unroll
  for (int p = 0; p < 8; ++p) {
    int row = p * 16 + (tid >> 4);
    int col = (tid & 15) * 8;
    *(f16x8*)(C + (size_t)(m0 + row) * N_TOT + n0 + col) =
        *(const f16x8*)&Ct[row * CT_PITCH + col];
  }
}

// ---------------- activation helper ----------------
__device__ __forceinline__ void act(float g, float v, float d, f16& xh, f16& ah) {
  float sg = 1.f / (1.f + __expf(-g));
  float tv = 1.f - 2.f / (__expf(2.f * v) + 1.f);
  float sd = 1.f / (1.f + __expf(-d));
  xh = (f16)(sg * tv);
  ah = (f16)(0.001f + 0.998f * sd);
}

// ---------------- cooperative fused scan ----------------
// 1024 blocks x 256 threads, 4 ch x 16 t per thread; xs/a stay in registers.
// u = [ck:8][b:2][cg:8]
__global__ __launch_bounds__(256, 4) void fused_scan_kernel(
    const f16* __restrict__ G, const float* __restrict__ bg,
    const float* __restrict__ bv, const float* __restrict__ bd,
    float* __restrict__ P, float* __restrict__ H, float* __restrict__ carry,
    float* __restrict__ out) {
  cg::grid_group grid = cg::this_grid();
  const int u = blockIdx.x * 256 + threadIdx.x;  // 0..262143
  const int cgi = u & 255;
  const int b = (u >> 8) & 3;
  const int ck = u >> 10;  // 0..255
  const int ch = cgi * 4;
  const int gs = b * CPB + ck;
  const int t0 = ck * CLEN;

  const f32x4 vbg = *(const f32x4*)(bg + ch);
  const f32x4 vbv = *(const f32x4*)(bv + ch);
  const f32x4 vbd = *(const f32x4*)(bd + ch);

  // phase 1: activations (registers) + chunk-local scan
  f16x4 xsr[CLEN], ar[CLEN];
  f32x4 h = {0.f, 0.f, 0.f, 0.f};
  f32x4 p = {1.f, 1.f, 1.f, 1.f};
#pragma unroll
  for (int i = 0; i < CLEN; ++i) {
    const size_t m = (size_t)b * S_LEN + (t0 + i);
    const f16* gp = G + m * N_TOT + ch;
    f16x4 g4 = *(const f16x4*)gp;
    f16x4 v4 = *(const f16x4*)(gp + D_DIM);
    f16x4 d4 = *(const f16x4*)(gp + 2 * D_DIM);
#pragma unroll
    for (int j = 0; j < 4; ++j) {
      f16 xh, ah;
      act((float)g4[j] + vbg[j], (float)v4[j] + vbv[j], (float)d4[j] + vbd[j], xh, ah);
      xsr[i][j] = xh;
      ar[i][j] = ah;
      // use ROUNDED values so phase-3 recomposition is exactly consistent
      float xf = (float)xh, af = (float)ah;
      h[j] = af * h[j] + xf;
      p[j] *= af;
    }
  }
  *(f32x4*)(P + (size_t)gs * D_DIM + ch) = p;
  *(f32x4*)(H + (size_t)gs * D_DIM + ch) = h;

  grid.sync();

  // phase 2: carry chain over chunks, one thread per (b,d) — 4096 threads
  if (u < B_DIM * D_DIM) {
    const int b2 = u >> 10;
    const int d2 = u & 1023;
    float hh = 0.f;
#pragma unroll 4
    for (int c = 0; c < CPB; ++c) {
      const size_t idx = (size_t)(b2 * CPB + c) * D_DIM + d2;
      carry[idx] = hh;
      hh = P[idx] * hh + H[idx];
    }
  }

  grid.sync();

  // phase 3: rescan from registers with carry, write f32 out
  f32x4 hc = *(const f32x4*)(carry + (size_t)gs * D_DIM + ch);
#pragma unroll
  for (int i = 0; i < CLEN; ++i) {
    const size_t m = (size_t)b * S_LEN + (t0 + i);
#pragma unroll
    for (int j = 0; j < 4; ++j)
      hc[j] = (float)ar[i][j] * hc[j] + (float)xsr[i][j];
    *(f32x4*)(out + m * D_DIM + ch) = hc;
  }
}

// ---------------- fallback 3-pass scan (R3-proven) ----------------
__global__ void scan1_kernel(const f16* __restrict__ G, const float* __restrict__ bg,
                             const float* __restrict__ bv, const float* __restrict__ bd,
                             f16* __restrict__ xsA, f16* __restrict__ aA,
                             float* __restrict__ P, float* __restrict__ H) {
  const int u = blockIdx.x * 256 + threadIdx.x;
  const int cgi = u & 127;
  const int b = (u >> 7) & 3;
  const int ck = u >> 9;
  const int ch = cgi * 8;
  float vbg[8], vbv[8], vbd[8];
  *(f32x4*)vbg = *(const f32x4*)(bg + ch); *(f32x4*)(vbg + 4) = *(const f32x4*)(bg + ch + 4);
  *(f32x4*)vbv = *(const f32x4*)(bv + ch); *(f32x4*)(vbv + 4) = *(const f32x4*)(bv + ch + 4);
  *(f32x4*)vbd = *(const f32x4*)(bd + ch); *(f32x4*)(vbd + 4) = *(const f32x4*)(bd + ch + 4);
  float h[8] = {}, p[8] = {1.f, 1.f, 1.f, 1.f, 1.f, 1.f, 1.f, 1.f};
  const int t0 = ck * CLEN;
#pragma unroll 2
  for (int t = t0; t < t0 + CLEN; ++t) {
    const size_t m = (size_t)b * S_LEN + t;
    const f16* gp = G + m * N_TOT + ch;
    f16x8 g8 = *(const f16x8*)gp;
    f16x8 v8 = *(const f16x8*)(gp + D_DIM);
    f16x8 d8 = *(const f16x8*)(gp + 2 * D_DIM);
    f16x8 xs8, a8;
#pragma unroll
    for (int j = 0; j < 8; ++j) {
      f16 xh, ah;
      act((float)g8[j] + vbg[j], (float)v8[j] + vbv[j], (float)d8[j] + vbd[j], xh, ah);
      float xsrv = (float)xh, avr = (float)ah;
      h[j] = avr * h[j] + xsrv;
      p[j] *= avr;
      xs8[j] = xh;
      a8[j] = ah;
    }
    *(f16x8*)(xsA + m * D_DIM + ch) = xs8;
    *(f16x8*)(aA + m * D_DIM + ch) = a8;
  }
  const int base = (b * CPB + ck) * D_DIM + ch;
  *(f32x4*)(P + base) = *(f32x4*)p;
  *(f32x4*)(P + base + 4) = *(f32x4*)(p + 4);
  *(f32x4*)(H + base) = *(f32x4*)h;
  *(f32x4*)(H + base + 4) = *(f32x4*)(h + 4);
}

__global__ void scan2_kernel(const float* __restrict__ P, const float* __restrict__ H,
                             float* __restrict__ carry) {
  const int idx = blockIdx.x * 256 + threadIdx.x;
  const int b = idx >> 10;
  const int d = idx & 1023;
  float h = 0.f;
  for (int c = 0; c < CPB; ++c) {
    int gsb = b * CPB + c;
    carry[gsb * D_DIM + d] = h;
    h = P[gsb * D_DIM + d] * h + H[gsb * D_DIM + d];
  }
}

__global__ void scan3_kernel(const f16* __restrict__ xsA, const f16* __restrict__ aA,
                             const float* __restrict__ carry, float* __restrict__ out) {
  const int u = blockIdx.x * 256 + threadIdx.x;
  const int cgi = u & 127;
  const int b = (u >> 7) & 3;
  const int ck = u >> 9;
  const int ch = cgi * 8;
  const int base = (b * CPB + ck) * D_DIM + ch;
  float h[8];
  *(f32x4*)h = *(const f32x4*)(carry + base);
  *(f32x4*)(h + 4) = *(const f32x4*)(carry + base + 4);
  const int t0 = ck * CLEN;
#pragma unroll 2
  for (int t = t0; t < t0 + CLEN; ++t) {
    const size_t m = (size_t)b * S_LEN + t;
    f16x8 xs8 = *(const f16x8*)(xsA + m * D_DIM + ch);
    f16x8 a8 = *(const f16x8*)(aA + m * D_DIM + ch);
#pragma unroll
    for (int j = 0; j < 8; ++j) h[j] = (float)a8[j] * h[j] + (float)xs8[j];
    float* op = out + m * D_DIM + ch;
    *(f32x4*)op = *(f32x4*)h;
    *(f32x4*)(op + 4) = *(f32x4*)(h + 4);
  }
}

extern "C" void kernel_launch(void* const* d_in, const int* in_sizes, int n_in,
                              void* d_out, int out_size, void* d_ws, size_t ws_size,
                              hipStream_t stream) {
  const float* x = (const float*)d_in[0];
  const float* Wg = (const float*)d_in[1];
  const float* bg = (const float*)d_in[2];
  const float* Wv = (const float*)d_in[3];
  const float* bv = (const float*)d_in[4];
  const float* Wd = (const float*)d_in[5];
  const float* bd = (const float*)d_in[6];
  float* out = (float*)d_out;

  // workspace layout (207,618,048 B total). Ah region (0..33.5MB) is dead
  // after the GEMM; P/H/carry (12 MB) overlay it.
  char* ws = (char*)d_ws;
  f16* Ah = (f16*)(ws);                     // 33,554,432 B (cvt -> gemm only)
  float* P = (float*)(ws);                  // NCHUNK*1024*4 = 4,194,304 B (overlay)
  float* H = (float*)(ws + 4194304);        // 4,194,304 B
  float* carry = (float*)(ws + 8388608);    // 4,194,304 B
  f16* Bh = (f16*)(ws + 33554432);          // 6,291,456 B
  f16* Gh = (f16*)(ws + 39845888);          // 100,663,296 B
  f16* xsA = (f16*)(ws + 140509184);        // 33,554,432 B (fallback only)
  f16* aA = (f16*)(ws + 174063616);         // 33,554,432 B (fallback only)

  cvt_all_kernel<<<9728, 256, 0, stream>>>(x, Wg, Wv, Wd, Ah, Bh);
  gemm_f16_kernel<<<dim3(N_TOT / BN, M_TOT / BM), 256, 0, stream>>>(Ah, Bh, Gh);

  // cooperative fused scan; deterministic fallback to 3-pass if unavailable
  void* args[] = {(void*)&Gh, (void*)&bg, (void*)&bv, (void*)&bd,
                  (void*)&P, (void*)&H, (void*)&carry, (void*)&out};
  hipError_t rc = hipLaunchCooperativeKernel((const void*)fused_scan_kernel,
                                             dim3(1024), dim3(256), args, 0, stream);
  if (rc != hipSuccess) {
    scan1_kernel<<<512, 256, 0, stream>>>(Gh, bg, bv, bd, xsA, aA, P, H);
    scan2_kernel<<<16, 256, 0, stream>>>(P, H, carry);
    scan3_kernel<<<512, 256, 0, stream>>>(xsA, aA, carry, out);
  }
}

// Round 6
// 327.521 us; speedup vs baseline: 1.8902x; 1.8902x over previous
//
#include <hip/hip_runtime.h>
#include <cstddef>
#include <cstdint>

// MinGRU: g/v/d = x@W{g,v,d}^T + b; xs = sigmoid(g)*tanh(v); a = 0.001+0.998*sigmoid(d)
// h_t = a_t*h_{t-1} + xs_t (causal scan over S). Output h [B,S,D] f32.
// B=4, S=4096, D=1024.
// R6: weight rows 3-way interleaved (B-row 3d+m = W{g,v,d} row d) so one BN=96
// GEMM block owns g,v,d for 32 channels; epilogue computes activations +
// per-16-row chunk P/H in-block. Kills G (98 MB wr + 100 MB rd) and scan1.
// Pipeline: cvt -> gemm_fused -> scan2 (carry chain) -> scan3 (rescan+out).

typedef _Float16 f16;
typedef f16 f16x8 __attribute__((ext_vector_type(8)));
typedef float f32x4 __attribute__((ext_vector_type(4)));

#define S_LEN 4096
#define D_DIM 1024
#define B_DIM 4
#define M_TOT (B_DIM * S_LEN)  // 16384
#define N_TOT (3 * D_DIM)      // 3072
#define K_TOT D_DIM            // 1024

#define CLEN 16
#define CPB (S_LEN / CLEN)   // 256 chunks per batch
#define NCHUNK (B_DIM * CPB) // 1024 total chunks

// ---------------- merged f32 -> f16 convert: x, then interleaved weights ----------------
__device__ __forceinline__ void cvt8(const float* s, f16* d) {
  f32x4 a = *(const f32x4*)s;
  f32x4 b = *(const f32x4*)(s + 4);
  f16x8 o;
  o[0] = (f16)a[0]; o[1] = (f16)a[1]; o[2] = (f16)a[2]; o[3] = (f16)a[3];
  o[4] = (f16)b[0]; o[5] = (f16)b[1]; o[6] = (f16)b[2]; o[7] = (f16)b[3];
  *(f16x8*)d = o;
}

__global__ void cvt_all_kernel(const float* __restrict__ x, const float* __restrict__ w0,
                               const float* __restrict__ w1, const float* __restrict__ w2,
                               f16* __restrict__ Ah, f16* __restrict__ Bh) {
  int i = (blockIdx.x * 256 + threadIdx.x) * 8;
  if (i < M_TOT * K_TOT) {
    cvt8(x + i, Ah + i);
  } else {
    int w = i - M_TOT * K_TOT;   // 0 .. 3*2^20
    int row = w >> 10;           // interleaved dst row 0..3071
    int col = w & 1023;
    int srow = row / 3;
    int mat = row - srow * 3;
    const float* s = (mat == 0) ? w0 : (mat == 1) ? w1 : w2;
    cvt8(s + srow * 1024 + col, Bh + w);
  }
}

// ---------------- fused GEMM + activation + chunk-local scan ----------------
#define BM 128
#define BN 96
#define BK 32
#define RAWP 100  // raw g/v/d tile pitch (halves)
#define XSP 32    // xs/a tile pitch (halves)

__device__ __forceinline__ void gl_lds16(const void* g, void* l) {
  __builtin_amdgcn_global_load_lds((const __attribute__((address_space(1))) void*)g,
                                   (__attribute__((address_space(3))) void*)l, 16, 0, 0);
}

__device__ __forceinline__ void act(float g, float v, float d, f16& xh, f16& ah) {
  float sg = 1.f / (1.f + __expf(-g));
  float tv = 1.f - 2.f / (__expf(2.f * v) + 1.f);
  float sd = 1.f / (1.f + __expf(-d));
  xh = (f16)(sg * tv);
  ah = (f16)(0.001f + 0.998f * sd);
}

// grid = (N_TOT/BN = 32, M_TOT/BM = 128), 256 threads.
__global__ __launch_bounds__(256) void gemm_fused_kernel(
    const f16* __restrict__ A, const f16* __restrict__ Bt,
    const float* __restrict__ bg, const float* __restrict__ bv,
    const float* __restrict__ bd,
    f16* __restrict__ xsA, f16* __restrict__ aA,
    float* __restrict__ P, float* __restrict__ H) {
  // LDS (halves): staging As[0,4096) Bs[4096,7168);
  // epilogue overlay: Raw[0,12800) (128x100), xsL[12800,16896), aL[16896,20992)
  __shared__ __attribute__((aligned(16))) f16 smem[20992];  // 41984 B
  f16* As = smem;
  f16* Bs = smem + 4096;
  const int tid = threadIdx.x;
  const int lane = tid & 63;
  const int wave = tid >> 6;
  const int m0 = blockIdx.y * BM;
  const int bn0 = blockIdx.x * BN;  // interleaved B row base (multiple of 3)

  // staging addressing: each round = 256 threads x 16 B = 64 rows of 32 halves
  const int srow = tid >> 2;
  const int scol = (tid & 3) * 8;
  const f16* aG0 = A + (size_t)(m0 + srow) * K_TOT + scol;
  const f16* aG1 = A + (size_t)(m0 + srow + 64) * K_TOT + scol;
  const f16* bG0 = Bt + (size_t)(bn0 + srow) * K_TOT + scol;
  const f16* bG1 = Bt + (size_t)(bn0 + 64 + (tid >> 2)) * K_TOT + scol;  // tid<128 only
  f16* aL0 = As + tid * 8;
  f16* aL1 = As + 2048 + tid * 8;
  f16* bL0 = Bs + tid * 8;
  f16* bL1 = Bs + 2048 + tid * 8;  // halves 2048..3071 (rows 64..95)

  const int wm = (wave >> 1) * 64;  // 0 / 64
  const int wn = (wave & 1) * 48;   // 0 / 48
  const int lm = lane & 15;
  const int kq = (lane >> 4) * 8;

  f32x4 acc[4][3] = {};

  for (int k0 = 0; k0 < K_TOT; k0 += BK) {
    gl_lds16(aG0 + k0, aL0);
    gl_lds16(aG1 + k0, aL1);
    gl_lds16(bG0 + k0, bL0);
    if (tid < 128) gl_lds16(bG1 + k0, bL1);
    __syncthreads();  // drains vmcnt -> staging visible
    f16x8 af[4], bf[3];
#pragma unroll
    for (int i = 0; i < 4; ++i)
      af[i] = *(const f16x8*)&As[(wm + i * 16 + lm) * BK + kq];
#pragma unroll
    for (int j = 0; j < 3; ++j)
      bf[j] = *(const f16x8*)&Bs[(wn + j * 16 + lm) * BK + kq];
#pragma unroll
    for (int i = 0; i < 4; ++i)
#pragma unroll
      for (int j = 0; j < 3; ++j)
        acc[i][j] = __builtin_amdgcn_mfma_f32_16x16x32_f16(af[i], bf[j], acc[i][j], 0, 0, 0);
    __syncthreads();  // protect LDS before next stage / epilogue overlay
  }

  // ---- epilogue 1: raw g/v/d -> LDS transpose tile (f16, same rounding as R3's G) ----
  f16* Raw = smem;
  const int r0 = wm + (lane >> 4) * 4;
  const int c0 = wn + (lane & 15);
#pragma unroll
  for (int i = 0; i < 4; ++i)
#pragma unroll
    for (int j = 0; j < 3; ++j)
#pragma unroll
      for (int r = 0; r < 4; ++r)
        Raw[(r0 + i * 16 + r) * RAWP + c0 + j * 16] = (f16)acc[i][j][r];
  __syncthreads();

  // ---- epilogue 2: activation + chunk-local scan; thread = (chunk c, channel d) ----
  f16* xsL = smem + 12800;
  f16* aL = smem + 16896;
  {
    const int d = tid & 31;
    const int c = tid >> 5;  // 0..7 (8 chunks of 16 rows)
    const int gd = (blockIdx.x << 5) + d;
    const float Bg = bg[gd], Bv = bv[gd], Bd_ = bd[gd];
    float p = 1.f, h = 0.f;
#pragma unroll
    for (int i = 0; i < CLEN; ++i) {
      const int r = c * CLEN + i;
      const f16* t3 = &Raw[r * RAWP + 3 * d];
      f16 xh, ah;
      act((float)t3[0] + Bg, (float)t3[1] + Bv, (float)t3[2] + Bd_, xh, ah);
      xsL[r * XSP + d] = xh;
      aL[r * XSP + d] = ah;
      // use ROUNDED values so scan3 recomposition is exactly consistent
      float xf = (float)xh, af_ = (float)ah;
      h = af_ * h + xf;
      p *= af_;
    }
    const int gs = (m0 >> 4) + c;  // global chunk index = m/16
    P[(size_t)gs * D_DIM + gd] = p;
    H[(size_t)gs * D_DIM + gd] = h;
  }
  __syncthreads();

  // ---- epilogue 3: coalesced xs/a global stores (2 rounds x 64 rows) ----
#pragma unroll
  for (int rr = 0; rr < 2; ++rr) {
    const int row = rr * 64 + (tid >> 2);
    const int col = (tid & 3) * 8;
    const size_t gi = (size_t)(m0 + row) * D_DIM + (blockIdx.x << 5) + col;
    *(f16x8*)(xsA + gi) = *(const f16x8*)&xsL[row * XSP + col];
    *(f16x8*)(aA + gi) = *(const f16x8*)&aL[row * XSP + col];
  }
}

// ---------------- scan pass 2: chain carries across 256 chunks per batch ----------------
__global__ void scan2_kernel(const float* __restrict__ P, const float* __restrict__ H,
                             float* __restrict__ carry) {
  const int idx = blockIdx.x * 256 + threadIdx.x;  // 0..4095 = b*1024+d
  const int b = idx >> 10;
  const int d = idx & 1023;
  float h = 0.f;
  for (int c = 0; c < CPB; ++c) {
    int gs = b * CPB + c;
    carry[gs * D_DIM + d] = h;
    h = P[gs * D_DIM + d] * h + H[gs * D_DIM + d];
  }
}

// ---------------- scan pass 3: rescan with carry, write output ----------------
__global__ void scan3_kernel(const f16* __restrict__ xsA, const f16* __restrict__ aA,
                             const float* __restrict__ carry, float* __restrict__ out) {
  const int u = blockIdx.x * 256 + threadIdx.x;
  const int cg = u & 127;
  const int b = (u >> 7) & 3;
  const int ck = u >> 9;  // 0..255
  const int ch = cg * 8;
  const int base = (b * CPB + ck) * D_DIM + ch;
  float h[8];
  *(f32x4*)h = *(const f32x4*)(carry + base);
  *(f32x4*)(h + 4) = *(const f32x4*)(carry + base + 4);
  const int t0 = ck * CLEN;
#pragma unroll 2
  for (int t = t0; t < t0 + CLEN; ++t) {
    const size_t m = (size_t)b * S_LEN + t;
    f16x8 xs8 = *(const f16x8*)(xsA + m * D_DIM + ch);
    f16x8 a8 = *(const f16x8*)(aA + m * D_DIM + ch);
#pragma unroll
    for (int j = 0; j < 8; ++j) h[j] = (float)a8[j] * h[j] + (float)xs8[j];
    float* op = out + m * D_DIM + ch;
    *(f32x4*)op = *(f32x4*)h;
    *(f32x4*)(op + 4) = *(f32x4*)(h + 4);
  }
}

extern "C" void kernel_launch(void* const* d_in, const int* in_sizes, int n_in,
                              void* d_out, int out_size, void* d_ws, size_t ws_size,
                              hipStream_t stream) {
  const float* x = (const float*)d_in[0];
  const float* Wg = (const float*)d_in[1];
  const float* bg = (const float*)d_in[2];
  const float* Wv = (const float*)d_in[3];
  const float* bv = (const float*)d_in[4];
  const float* Wd = (const float*)d_in[5];
  const float* bd = (const float*)d_in[6];
  float* out = (float*)d_out;

  // workspace layout (~120 MB), NO overlays: P/H are written by gemm_fused
  // while other blocks still read Ah.
  char* ws = (char*)d_ws;
  f16* Ah = (f16*)(ws);                     // 33,554,432 B
  f16* Bh = (f16*)(ws + 33554432);          // 6,291,456 B (interleaved weights)
  f16* xsA = (f16*)(ws + 39845888);         // 33,554,432 B
  f16* aA = (f16*)(ws + 73400320);          // 33,554,432 B
  float* P = (float*)(ws + 106954752);      // NCHUNK*1024*4 = 4,194,304 B
  float* H = (float*)(ws + 111149056);      // 4,194,304 B
  float* carry = (float*)(ws + 115343360);  // 4,194,304 B

  cvt_all_kernel<<<9728, 256, 0, stream>>>(x, Wg, Wv, Wd, Ah, Bh);
  gemm_fused_kernel<<<dim3(N_TOT / BN, M_TOT / BM), 256, 0, stream>>>(
      Ah, Bh, bg, bv, bd, xsA, aA, P, H);
  scan2_kernel<<<16, 256, 0, stream>>>(P, H, carry);
  scan3_kernel<<<512, 256, 0, stream>>>(xsA, aA, carry, out);
}